// Round 1
// 3900.303 us; speedup vs baseline: 2.7084x; 2.7084x over previous
//
#include <hip/hip_runtime.h>

#define N_DIM 100000
#define M_DIM 200000
#define NNZ_A 2000000
#define NNZ_P 500000
#define NMSUM 300000
#define NM1   300001
#define CG_ITERS 20
#define TPB 256
#define NSLOT 512

// slots: sc[0]=xTPx, sc[1..3]=dd_t dots, sc[8..9]=rhs-FTmv dots,
// per-iter base 16+8*it: {d1,d2,e1,e2,pq}, gam[] at sc+432 (0..50)

__device__ __forceinline__ void blk_red_add(double v, double* dst) {
    __shared__ double sb[TPB];
    int tid = threadIdx.x;
    __syncthreads();
    sb[tid] = v;
    __syncthreads();
    for (int sh = TPB / 2; sh > 0; sh >>= 1) {
        if (tid < sh) sb[tid] += sb[tid + sh];
        __syncthreads();
    }
    if (tid == 0) atomicAdd(dst, sb[0]);
}

// ---------------- setup: init + histogram + scan + fill ----------------
__global__ __launch_bounds__(TPB) void k_init(double* sc, const float* y, const float* s,
                                              const float* x, double* mask_d, double* pim_d,
                                              double* xd, double* xcg,
                                              int* cntR, int* cntC, int* cntP) {
    long i = (long)blockIdx.x * TPB + threadIdx.x;
    if (i < NSLOT) sc[i] = 0.0;
    if (i < M_DIM) {
        double v = (double)y[i] - (double)s[i];
        mask_d[i] = v > 0.0 ? 1.0 : 0.0;
        pim_d[i]  = v > 0.0 ? v : 0.0;
        cntR[i] = 0;
    }
    if (i < N_DIM) { xd[i] = (double)x[i]; cntC[i] = 0; cntP[i] = 0; }
    if (i < NM1) xcg[i] = 0.0;
}

__global__ __launch_bounds__(TPB) void k_hist(const int* Ar, const int* Ac, const int* Pr,
                                              int* cntR, int* cntC, int* cntP) {
    long k = (long)blockIdx.x * TPB + threadIdx.x;
    if (k < NNZ_A) {
        atomicAdd(&cntR[Ar[k]], 1);
        atomicAdd(&cntC[Ac[k]], 1);
    }
    if (k < NNZ_P) atomicAdd(&cntP[Pr[k]], 1);
}

__global__ __launch_bounds__(TPB) void k_scan1(const int* cnt, int len, int* exc, int* blksum) {
    __shared__ int sb[TPB];
    int i = blockIdx.x * TPB + threadIdx.x;
    int v = (i < len) ? cnt[i] : 0;
    sb[threadIdx.x] = v;
    __syncthreads();
    for (int sh = 1; sh < TPB; sh <<= 1) {
        int t = (threadIdx.x >= sh) ? sb[threadIdx.x - sh] : 0;
        __syncthreads();
        sb[threadIdx.x] += t;
        __syncthreads();
    }
    if (i < len) exc[i] = sb[threadIdx.x] - v;
    if (threadIdx.x == TPB - 1) blksum[blockIdx.x] = sb[TPB - 1];
}

__global__ __launch_bounds__(1024) void k_scan2(int* blksum, int nb, int* total_out) {
    __shared__ int sb[1024];
    int t = threadIdx.x;
    int v = (t < nb) ? blksum[t] : 0;
    sb[t] = v;
    __syncthreads();
    for (int sh = 1; sh < 1024; sh <<= 1) {
        int x = (t >= sh) ? sb[t - sh] : 0;
        __syncthreads();
        sb[t] += x;
        __syncthreads();
    }
    if (t < nb) blksum[t] = sb[t] - v;          // exclusive block offsets
    if (t == nb - 1) *total_out = sb[t];        // rptr[len] = total
}

__global__ __launch_bounds__(TPB) void k_scan3(int* exc, const int* blksum, int len, int* cur) {
    int i = blockIdx.x * TPB + threadIdx.x;
    if (i < len) {
        int v = exc[i] + blksum[blockIdx.x];
        exc[i] = v;
        cur[i] = v;
    }
}

__global__ __launch_bounds__(TPB) void k_fill(const int* Ar, const int* Ac, const float* Av,
                                              const float* dAv, const int* Pr, const int* Pc,
                                              const float* Pv, const float* dPv,
                                              int* curR, int* curC, int* curP,
                                              int2* pAr, float* dvalAr,
                                              int2* pAc, float* dvalAc,
                                              int2* pP, float* dvalP) {
    long k = (long)blockIdx.x * TPB + threadIdx.x;
    if (k < NNZ_A) {
        int r0 = Ar[k], c0 = Ac[k];
        float v = Av[k], dv = dAv[k];
        int p1 = atomicAdd(&curR[r0], 1);
        pAr[p1] = make_int2(c0, __float_as_int(v));
        dvalAr[p1] = dv;
        int p2 = atomicAdd(&curC[c0], 1);
        pAc[p2] = make_int2(r0, __float_as_int(v));
        dvalAc[p2] = dv;
    }
    if (k < NNZ_P) {
        int r0 = Pr[k];
        int p3 = atomicAdd(&curP[r0], 1);
        pP[p3] = make_int2(Pc[k], __float_as_int(Pv[k]));
        dvalP[p3] = dPv[k];
    }
}

// ---------------- generic CSR gather SpMV (setup) ----------------
__global__ __launch_bounds__(TPB) void k_csr(const int* rptr, const int2* pair,
                                             const double* vin, double* vout,
                                             double sgn, int accum, int nrows) {
    int i = blockIdx.x * TPB + threadIdx.x;
    if (i >= nrows) return;
    double s = 0.0;
    int e = rptr[i + 1];
    for (int k = rptr[i]; k < e; ++k) {
        int2 ev = pair[k];
        s += (double)__int_as_float(ev.y) * vin[ev.x];
    }
    s *= sgn;
    vout[i] = accum ? (vout[i] + s) : s;
}

__global__ __launch_bounds__(TPB) void k_csr_d(const int* rptr, const int2* pair,
                                               const float* dval, const double* vin,
                                               double* vout, double sgn, int accum, int nrows) {
    int i = blockIdx.x * TPB + threadIdx.x;
    if (i >= nrows) return;
    double s = 0.0;
    int e = rptr[i + 1];
    for (int k = rptr[i]; k < e; ++k)
        s += (double)dval[k] * vin[pair[k].x];
    s *= sgn;
    vout[i] = accum ? (vout[i] + s) : s;
}

// ---------------- dots & small elementwise (unchanged math) ----------------
__global__ __launch_bounds__(TPB) void k_dot_fd(const float* a, const double* b, long len, double* dst) {
    long i = (long)blockIdx.x * TPB + threadIdx.x;
    double loc = 0.0;
    if (i < len) loc = (double)a[i] * b[i];
    blk_red_add(loc, dst);
}
__global__ __launch_bounds__(TPB) void k_dot_ff(const float* a, const float* b, long len, double* dst) {
    long i = (long)blockIdx.x * TPB + threadIdx.x;
    double loc = 0.0;
    if (i < len) loc = (double)a[i] * (double)b[i];
    blk_red_add(loc, dst);
}
__global__ __launch_bounds__(TPB) void k_c3e(const float* q, const double* Px, double* c3) {
    int i = blockIdx.x * TPB + threadIdx.x;
    if (i < N_DIM) c3[i] = (double)q[i] + 2.0 * Px[i];
}
__global__ __launch_bounds__(TPB) void k_dd_n(const double* dpx, const float* dq, double* dd) {
    int i = blockIdx.x * TPB + threadIdx.x;
    if (i < N_DIM) dd[i] = dpx[i] + (double)dq[i];
}
__global__ __launch_bounds__(TPB) void k_dd_m(const float* db, double* dd) {
    int j = blockIdx.x * TPB + threadIdx.x;
    if (j < M_DIM) dd[N_DIM + j] += (double)db[j];
}
__global__ __launch_bounds__(64) void k_dd_t(double* sc, double* dd) {
    if (threadIdx.x == 0) dd[NMSUM] = -sc[1] - sc[2] - sc[3];
}
__global__ __launch_bounds__(TPB) void k_neg(double* dd) {
    int i = blockIdx.x * TPB + threadIdx.x;
    if (i < NM1) dd[i] = -dd[i];
}
__global__ __launch_bounds__(TPB) void k_ft_n(const double* c3, const double* W, double* U) {
    int i = blockIdx.x * TPB + threadIdx.x;
    if (i < N_DIM) U[i] = U[i] - c3[i] * W[NMSUM];
}
__global__ __launch_bounds__(TPB) void k_ft_m(const double* mask_d, const float* b,
                                              const double* tm, const double* W, double* U) {
    int j = blockIdx.x * TPB + threadIdx.x;
    if (j < M_DIM) {
        double wt = W[NMSUM];
        double tmv = tm[j] - (double)b[j] * wt;
        double wm = W[N_DIM + j];
        U[N_DIM + j] = mask_d[j] * (tmv - wm) + wm;
    }
}
__global__ __launch_bounds__(64) void k_ft_t(const double* e1, const double* e2, const double* xtpx,
                                             const double* W, double* U) {
    if (threadIdx.x == 0) U[NMSUM] = (*e1) + (*e2) + (*xtpx) * W[NMSUM];
}
__global__ __launch_bounds__(TPB) void k_cginit(const double* r, double* p, double* gam0) {
    int i = blockIdx.x * TPB + threadIdx.x;
    double loc = 0.0;
    if (i < NM1) { double v = r[i]; p[i] = v; loc = v * v; }
    blk_red_add(loc, gam0);
}

// ---------------- fused per-iteration kernels (4 launches/iter) ----------------
// K1: p-update + um + d1 = c3.p_n, d2 = b.um   (no zeroing needed any more)
__global__ __launch_bounds__(TPB) void k_iterA(const double* r, double* p,
                                               const double* mask_d, const double* c3,
                                               const float* b, double* um,
                                               double* sc, int it) {
    long i = (long)blockIdx.x * TPB + threadIdx.x;
    double* gam = sc + 432;
    double* base = sc + 16 + 8 * it;
    double l1 = 0.0, l2 = 0.0;
    if (i < NM1) {
        double pn;
        if (it > 0) {
            double beta = gam[it] / gam[it - 1];
            pn = r[i] + beta * p[i];
            p[i] = pn;
        } else {
            pn = p[i];
        }
        if (i < N_DIM) {
            l1 = c3[i] * pn;
        } else if (i < NMSUM) {
            int j = (int)(i - N_DIM);
            double u = mask_d[j] * pn;
            um[j] = u;
            l2 = (double)b[j] * u;
        }
    }
    blk_red_add(l1, base);       // d1
    blk_red_add(l2, base + 1);   // d2
}

// K2: Fmv — CSR gathers + elementwise finish + e1,e2 dots, all fused
__global__ __launch_bounds__(TPB) void k_fmv(const int* __restrict__ rptrP, const int2* __restrict__ pP,
                                             const int* __restrict__ rptrAc, const int2* __restrict__ pAc,
                                             const int* __restrict__ rptrAr, const int2* __restrict__ pAr,
                                             const float* __restrict__ q, const float* __restrict__ b,
                                             const double* __restrict__ p, const double* __restrict__ um,
                                             double* __restrict__ Fp, double* sc, int it) {
    long i = (long)blockIdx.x * TPB + threadIdx.x;
    double* base = sc + 16 + 8 * it;
    double ut = p[NMSUM];
    double l1 = 0.0, l2 = 0.0;
    if (i < N_DIM) {
        double s = 0.0;
        int e = rptrP[i + 1];
        for (int k = rptrP[i]; k < e; ++k) {
            int2 ev = pP[k];
            s += (double)__int_as_float(ev.y) * p[ev.x];
        }
        int e2 = rptrAc[i + 1];
        for (int k = rptrAc[i]; k < e2; ++k) {
            int2 ev = pAc[k];
            s += (double)__int_as_float(ev.y) * um[ev.x];
        }
        double r1 = s + (double)q[i] * ut;
        double v = (r1 - p[i]) + p[i];
        Fp[i] = v;
        l1 = (double)q[i] * v;
    } else if (i < NMSUM) {
        int j = (int)(i - N_DIM);
        double s = 0.0;
        int e = rptrAr[j + 1];
        for (int k = rptrAr[j]; k < e; ++k) {
            int2 ev = pAr[k];
            s += (double)__int_as_float(ev.y) * p[ev.x];
        }
        double r2 = -s + (double)b[j] * ut;
        double v = (r2 - um[j]) + p[i];
        Fp[i] = v;
        l2 = (double)b[j] * v;
    } else if (i == NMSUM) {
        double r3 = -base[0] - base[1] + sc[0] * ut;
        Fp[NMSUM] = (r3 - ut) + ut;
    }
    blk_red_add(l1, base + 2);   // e1
    blk_red_add(l2, base + 3);   // e2
}

// K3: FTmv — CSR gathers + elementwise finish + pq dot, all fused
__global__ __launch_bounds__(TPB) void k_ftmv(const int* __restrict__ rptrP, const int2* __restrict__ pP,
                                              const int* __restrict__ rptrAc, const int2* __restrict__ pAc,
                                              const int* __restrict__ rptrAr, const int2* __restrict__ pAr,
                                              const float* __restrict__ b, const double* __restrict__ mask_d,
                                              const double* __restrict__ c3,
                                              const double* __restrict__ Fp, const double* __restrict__ p,
                                              double* __restrict__ Ap, double* sc, int it) {
    long i = (long)blockIdx.x * TPB + threadIdx.x;
    double* base = sc + 16 + 8 * it;
    double wt = Fp[NMSUM];
    double l = 0.0;
    if (i < N_DIM) {
        double s = 0.0;
        int e = rptrP[i + 1];
        for (int k = rptrP[i]; k < e; ++k) {
            int2 ev = pP[k];
            s += (double)__int_as_float(ev.y) * Fp[ev.x];
        }
        int e2 = rptrAc[i + 1];
        for (int k = rptrAc[i]; k < e2; ++k) {
            int2 ev = pAc[k];
            s -= (double)__int_as_float(ev.y) * Fp[N_DIM + ev.x];
        }
        double v = s - c3[i] * wt;
        Ap[i] = v;
        l = p[i] * v;
    } else if (i < NMSUM) {
        int j = (int)(i - N_DIM);
        double s = 0.0;
        int e = rptrAr[j + 1];
        for (int k = rptrAr[j]; k < e; ++k) {
            int2 ev = pAr[k];
            s += (double)__int_as_float(ev.y) * Fp[ev.x];
        }
        double tmv = s - (double)b[j] * wt;
        double wm = Fp[i];
        double v = mask_d[j] * (tmv - wm) + wm;
        Ap[i] = v;
        l = p[i] * v;
    } else if (i == NMSUM) {
        double tt = base[2] + base[3] + sc[0] * wt;
        Ap[i] = tt;
        l = p[i] * tt;
    }
    blk_red_add(l, base + 4);   // pq
}

// K4: x,r update + gam[it+1]
__global__ __launch_bounds__(TPB) void k_upd(const double* p, const double* Ap,
                                             double* xcg, double* r, double* sc, int it) {
    long i = (long)blockIdx.x * TPB + threadIdx.x;
    double* gam = sc + 432;
    double* base = sc + 16 + 8 * it;
    double alpha = gam[it] / base[4];
    double l = 0.0;
    if (i < NM1) {
        xcg[i] += alpha * p[i];
        double rn = r[i] - alpha * Ap[i];
        r[i] = rn;
        l = rn * rn;
    }
    blk_red_add(l, &gam[it + 1]);
}

__global__ __launch_bounds__(TPB) void k_final(const double* xcg, const double* mask_d,
                                               const float* x, const float* y, const float* s,
                                               float* out) {
    int i = blockIdx.x * TPB + threadIdx.x;
    double dzt = xcg[NMSUM];
    if (i < N_DIM) {
        out[i] = (float)(xcg[i] - (double)x[i] * dzt);
    } else if (i < NMSUM) {
        int j = i - N_DIM;
        double dzm = xcg[N_DIM + j];
        double t = mask_d[j] * dzm;
        out[N_DIM + j] = (float)(t - (double)y[j] * dzt);
        out[N_DIM + M_DIM + j] = (float)(t - dzm - (double)s[j] * dzt);
    }
}

extern "C" void kernel_launch(void* const* d_in, const int* in_sizes, int n_in,
                              void* d_out, int out_size, void* d_ws, size_t ws_size,
                              hipStream_t stream) {
    const int*   Pr  = (const int*)d_in[0];
    const int*   Pc  = (const int*)d_in[1];
    const float* Pv  = (const float*)d_in[2];
    const int*   Ar  = (const int*)d_in[3];
    const int*   Ac  = (const int*)d_in[4];
    const float* Av  = (const float*)d_in[5];
    const float* q   = (const float*)d_in[6];
    const float* b   = (const float*)d_in[7];
    const float* x   = (const float*)d_in[8];
    const float* yv  = (const float*)d_in[9];
    const float* sv  = (const float*)d_in[10];
    const float* dPv = (const float*)d_in[11];
    const float* dAv = (const float*)d_in[12];
    const float* dq  = (const float*)d_in[13];
    const float* db  = (const float*)d_in[14];
    float* out = (float*)d_out;

    char* wp = (char*)d_ws;
    auto alloc = [&](size_t bytes) { char* r0 = wp; wp += (bytes + 255) & ~255ull; return r0; };

    // 8B-aligned doubles / pairs first
    double* sc     = (double*)alloc(NSLOT * 8);
    double* mask_d = (double*)alloc((size_t)M_DIM * 8);
    double* pim_d  = (double*)alloc((size_t)M_DIM * 8);
    double* xd     = (double*)alloc((size_t)N_DIM * 8);
    double* Px     = (double*)alloc((size_t)N_DIM * 8);
    double* dpx    = (double*)alloc((size_t)N_DIM * 8);
    double* c3     = (double*)alloc((size_t)N_DIM * 8);
    double* um     = (double*)alloc((size_t)M_DIM * 8);
    double* tm     = (double*)alloc((size_t)M_DIM * 8);
    double* dd     = (double*)alloc((size_t)NM1 * 8);
    double* r      = (double*)alloc((size_t)NM1 * 8);
    double* p      = (double*)alloc((size_t)NM1 * 8);
    double* xcg    = (double*)alloc((size_t)NM1 * 8);
    double* Fp     = (double*)alloc((size_t)NM1 * 8);
    double* Ap     = (double*)alloc((size_t)NM1 * 8);
    int2*  pAr    = (int2*)alloc((size_t)NNZ_A * 8);
    int2*  pAc    = (int2*)alloc((size_t)NNZ_A * 8);
    int2*  pP     = (int2*)alloc((size_t)NNZ_P * 8);
    // 4B arrays
    float* dvalAr = (float*)alloc((size_t)NNZ_A * 4);
    float* dvalAc = (float*)alloc((size_t)NNZ_A * 4);
    float* dvalP  = (float*)alloc((size_t)NNZ_P * 4);
    int*   rptrAr = (int*)alloc((size_t)(M_DIM + 1) * 4);
    int*   rptrAc = (int*)alloc((size_t)(N_DIM + 1) * 4);
    int*   rptrP  = (int*)alloc((size_t)(N_DIM + 1) * 4);
    int*   cntR   = (int*)alloc((size_t)M_DIM * 4);   // reused as cursor
    int*   cntC   = (int*)alloc((size_t)N_DIM * 4);
    int*   cntP   = (int*)alloc((size_t)N_DIM * 4);
    int*   blks   = (int*)alloc(1024 * 4);

    double* xtpx = sc + 0;
    double* gam  = sc + 432;

    auto g = [](long n) { return dim3((unsigned)((n + TPB - 1) / TPB)); };

    // ---- CSR build ----
    hipLaunchKernelGGL(k_init, g(NM1), dim3(TPB), 0, stream, sc, yv, sv, x, mask_d, pim_d, xd, xcg, cntR, cntC, cntP);
    hipLaunchKernelGGL(k_hist, g(NNZ_A), dim3(TPB), 0, stream, Ar, Ac, Pr, cntR, cntC, cntP);

    auto scan = [&](int* cnt, int len, int* rptr) {
        int nb = (len + TPB - 1) / TPB;
        hipLaunchKernelGGL(k_scan1, dim3((unsigned)nb), dim3(TPB), 0, stream, cnt, len, rptr, blks);
        hipLaunchKernelGGL(k_scan2, dim3(1), dim3(1024), 0, stream, blks, nb, rptr + len);
        hipLaunchKernelGGL(k_scan3, dim3((unsigned)nb), dim3(TPB), 0, stream, rptr, blks, len, cnt);
    };
    scan(cntR, M_DIM, rptrAr);   // cntR becomes cursor
    scan(cntC, N_DIM, rptrAc);
    scan(cntP, N_DIM, rptrP);

    hipLaunchKernelGGL(k_fill, g(NNZ_A), dim3(TPB), 0, stream, Ar, Ac, Av, dAv, Pr, Pc, Pv, dPv,
                       cntR, cntC, cntP, pAr, dvalAr, pAc, dvalAc, pP, dvalP);

    // ---- setup math (same sequence as before, scatters -> CSR gathers) ----
    hipLaunchKernelGGL(k_csr, g(N_DIM), dim3(TPB), 0, stream, rptrP, pP, xd, Px, 1.0, 0, N_DIM);          // Px = P x
    hipLaunchKernelGGL(k_dot_fd, g(N_DIM), dim3(TPB), 0, stream, x, Px, (long)N_DIM, xtpx);
    hipLaunchKernelGGL(k_c3e, g(N_DIM), dim3(TPB), 0, stream, q, Px, c3);
    hipLaunchKernelGGL(k_csr_d, g(N_DIM), dim3(TPB), 0, stream, rptrP, pP, dvalP, xd, dpx, 1.0, 0, N_DIM); // dpx = dP x
    hipLaunchKernelGGL(k_dd_n, g(N_DIM), dim3(TPB), 0, stream, dpx, dq, dd);
    hipLaunchKernelGGL(k_csr_d, g(N_DIM), dim3(TPB), 0, stream, rptrAc, pAc, dvalAc, pim_d, dd, 1.0, 1, N_DIM);   // += dA^T pim
    hipLaunchKernelGGL(k_csr_d, g(M_DIM), dim3(TPB), 0, stream, rptrAr, pAr, dvalAr, xd, dd + N_DIM, -1.0, 0, M_DIM); // -dA x
    hipLaunchKernelGGL(k_dd_m, g(M_DIM), dim3(TPB), 0, stream, db, dd);
    hipLaunchKernelGGL(k_dot_ff, g(N_DIM), dim3(TPB), 0, stream, dq, x, (long)N_DIM, sc + 1);
    hipLaunchKernelGGL(k_dot_fd, g(M_DIM), dim3(TPB), 0, stream, db, pim_d, (long)M_DIM, sc + 2);
    hipLaunchKernelGGL(k_dot_fd, g(N_DIM), dim3(TPB), 0, stream, x, dpx, (long)N_DIM, sc + 3);
    hipLaunchKernelGGL(k_dd_t, dim3(1), dim3(64), 0, stream, sc, dd);
    hipLaunchKernelGGL(k_neg, g(NM1), dim3(TPB), 0, stream, dd);
    hipLaunchKernelGGL(k_csr, g(N_DIM), dim3(TPB), 0, stream, rptrP, pP, dd, r, 1.0, 0, N_DIM);            // r_n = P wn
    hipLaunchKernelGGL(k_csr, g(N_DIM), dim3(TPB), 0, stream, rptrAc, pAc, dd + N_DIM, r, -1.0, 1, N_DIM); // -= A^T wm
    hipLaunchKernelGGL(k_ft_n, g(N_DIM), dim3(TPB), 0, stream, c3, dd, r);
    hipLaunchKernelGGL(k_csr, g(M_DIM), dim3(TPB), 0, stream, rptrAr, pAr, dd, tm, 1.0, 0, M_DIM);         // tm = A wn
    hipLaunchKernelGGL(k_ft_m, g(M_DIM), dim3(TPB), 0, stream, mask_d, b, tm, dd, r);
    hipLaunchKernelGGL(k_dot_fd, g(N_DIM), dim3(TPB), 0, stream, q, dd, (long)N_DIM, sc + 8);
    hipLaunchKernelGGL(k_dot_fd, g(M_DIM), dim3(TPB), 0, stream, b, dd + N_DIM, (long)M_DIM, sc + 9);
    hipLaunchKernelGGL(k_ft_t, dim3(1), dim3(64), 0, stream, sc + 8, sc + 9, xtpx, dd, r);
    hipLaunchKernelGGL(k_cginit, g(NM1), dim3(TPB), 0, stream, r, p, gam);

    // ---- 20 CG iterations, 4 fused launches each ----
    for (int it = 0; it < CG_ITERS; ++it) {
        hipLaunchKernelGGL(k_iterA, g(NM1), dim3(TPB), 0, stream, r, p, mask_d, c3, b, um, sc, it);
        hipLaunchKernelGGL(k_fmv,   g(NM1), dim3(TPB), 0, stream, rptrP, pP, rptrAc, pAc, rptrAr, pAr,
                           q, b, p, um, Fp, sc, it);
        hipLaunchKernelGGL(k_ftmv,  g(NM1), dim3(TPB), 0, stream, rptrP, pP, rptrAc, pAc, rptrAr, pAr,
                           b, mask_d, c3, Fp, p, Ap, sc, it);
        hipLaunchKernelGGL(k_upd,   g(NM1), dim3(TPB), 0, stream, p, Ap, xcg, r, sc, it);
    }

    hipLaunchKernelGGL(k_final, g(NMSUM), dim3(TPB), 0, stream, xcg, mask_d, x, yv, sv, out);
}

// Round 2
// 3638.309 us; speedup vs baseline: 2.9034x; 1.0720x over previous
//
#include <hip/hip_runtime.h>

#define N_DIM 100000
#define M_DIM 200000
#define NNZ_A 2000000
#define NNZ_P 500000
#define NMSUM 300000
#define NM1   300001
#define CG_ITERS 20
#define TPB 256
#define NSLOT 512

// slots: sc[0]=xTPx, sc[1..3]=dd_t dots, sc[8..9]=rhs-FTmv dots,
// per-iter base 16+8*it: {d1,d2,e1,e2,pq}, gam[] at sc+432 (0..50)

__device__ __forceinline__ void blk_red_add(double v, double* dst) {
    __shared__ double sb[TPB];
    int tid = threadIdx.x;
    __syncthreads();
    sb[tid] = v;
    __syncthreads();
    for (int sh = TPB / 2; sh > 0; sh >>= 1) {
        if (tid < sh) sb[tid] += sb[tid + sh];
        __syncthreads();
    }
    if (tid == 0) atomicAdd(dst, sb[0]);
}

// 4-way unrolled CSR row gather: 4 independent pair loads then 4 gathers → MLP ~4
__device__ __forceinline__ double row_dot(const int2* __restrict__ pair, int beg, int end,
                                          const double* __restrict__ vin) {
    double s = 0.0;
    int k = beg;
    for (; k + 4 <= end; k += 4) {
        int2 a0 = pair[k];
        int2 a1 = pair[k + 1];
        int2 a2 = pair[k + 2];
        int2 a3 = pair[k + 3];
        double g0 = vin[a0.x];
        double g1 = vin[a1.x];
        double g2 = vin[a2.x];
        double g3 = vin[a3.x];
        s += (double)__int_as_float(a0.y) * g0;
        s += (double)__int_as_float(a1.y) * g1;
        s += (double)__int_as_float(a2.y) * g2;
        s += (double)__int_as_float(a3.y) * g3;
    }
    for (; k < end; ++k) {
        int2 a = pair[k];
        s += (double)__int_as_float(a.y) * vin[a.x];
    }
    return s;
}

__device__ __forceinline__ double row_dot_d(const int2* __restrict__ pair,
                                            const float* __restrict__ dval, int beg, int end,
                                            const double* __restrict__ vin) {
    double s = 0.0;
    int k = beg;
    for (; k + 4 <= end; k += 4) {
        int c0 = pair[k].x, c1 = pair[k + 1].x, c2 = pair[k + 2].x, c3v = pair[k + 3].x;
        float d0 = dval[k], d1 = dval[k + 1], d2 = dval[k + 2], d3 = dval[k + 3];
        double g0 = vin[c0], g1 = vin[c1], g2 = vin[c2], g3 = vin[c3v];
        s += (double)d0 * g0;
        s += (double)d1 * g1;
        s += (double)d2 * g2;
        s += (double)d3 * g3;
    }
    for (; k < end; ++k)
        s += (double)dval[k] * vin[pair[k].x];
    return s;
}

// ---------------- setup: init + histogram + scan + fill ----------------
__global__ __launch_bounds__(TPB) void k_init(double* sc, const float* y, const float* s,
                                              const float* x, double* mask_d, double* pim_d,
                                              double* xd, double* xcg,
                                              int* cntR, int* cntC, int* cntP) {
    long i = (long)blockIdx.x * TPB + threadIdx.x;
    if (i < NSLOT) sc[i] = 0.0;
    if (i < M_DIM) {
        double v = (double)y[i] - (double)s[i];
        mask_d[i] = v > 0.0 ? 1.0 : 0.0;
        pim_d[i]  = v > 0.0 ? v : 0.0;
        cntR[i] = 0;
    }
    if (i < N_DIM) { xd[i] = (double)x[i]; cntC[i] = 0; cntP[i] = 0; }
    if (i < NM1) xcg[i] = 0.0;
}

__global__ __launch_bounds__(TPB) void k_hist(const int* Ar, const int* Ac, const int* Pr,
                                              int* cntR, int* cntC, int* cntP) {
    long k = (long)blockIdx.x * TPB + threadIdx.x;
    if (k < NNZ_A) {
        atomicAdd(&cntR[Ar[k]], 1);
        atomicAdd(&cntC[Ac[k]], 1);
    }
    if (k < NNZ_P) atomicAdd(&cntP[Pr[k]], 1);
}

__global__ __launch_bounds__(TPB) void k_scan1(const int* cnt, int len, int* exc, int* blksum) {
    __shared__ int sb[TPB];
    int i = blockIdx.x * TPB + threadIdx.x;
    int v = (i < len) ? cnt[i] : 0;
    sb[threadIdx.x] = v;
    __syncthreads();
    for (int sh = 1; sh < TPB; sh <<= 1) {
        int t = (threadIdx.x >= sh) ? sb[threadIdx.x - sh] : 0;
        __syncthreads();
        sb[threadIdx.x] += t;
        __syncthreads();
    }
    if (i < len) exc[i] = sb[threadIdx.x] - v;
    if (threadIdx.x == TPB - 1) blksum[blockIdx.x] = sb[TPB - 1];
}

__global__ __launch_bounds__(1024) void k_scan2(int* blksum, int nb, int* total_out) {
    __shared__ int sb[1024];
    int t = threadIdx.x;
    int v = (t < nb) ? blksum[t] : 0;
    sb[t] = v;
    __syncthreads();
    for (int sh = 1; sh < 1024; sh <<= 1) {
        int x = (t >= sh) ? sb[t - sh] : 0;
        __syncthreads();
        sb[t] += x;
        __syncthreads();
    }
    if (t < nb) blksum[t] = sb[t] - v;          // exclusive block offsets
    if (t == nb - 1) *total_out = sb[t];        // rptr[len] = total
}

__global__ __launch_bounds__(TPB) void k_scan3(int* exc, const int* blksum, int len, int* cur) {
    int i = blockIdx.x * TPB + threadIdx.x;
    if (i < len) {
        int v = exc[i] + blksum[blockIdx.x];
        exc[i] = v;
        cur[i] = v;
    }
}

// Split fills: each kernel's scatter working set fits aggregate L2 (line re-use before eviction)
__global__ __launch_bounds__(TPB) void k_fillAr(const int* Ar, const int* Ac, const float* Av,
                                                const float* dAv, int* curR,
                                                int2* pAr, float* dvalAr) {
    long k = (long)blockIdx.x * TPB + threadIdx.x;
    if (k < NNZ_A) {
        int pos = atomicAdd(&curR[Ar[k]], 1);
        pAr[pos] = make_int2(Ac[k], __float_as_int(Av[k]));
        dvalAr[pos] = dAv[k];
    }
}
__global__ __launch_bounds__(TPB) void k_fillAc(const int* Ar, const int* Ac, const float* Av,
                                                const float* dAv, int* curC,
                                                int2* pAc, float* dvalAc) {
    long k = (long)blockIdx.x * TPB + threadIdx.x;
    if (k < NNZ_A) {
        int pos = atomicAdd(&curC[Ac[k]], 1);
        pAc[pos] = make_int2(Ar[k], __float_as_int(Av[k]));
        dvalAc[pos] = dAv[k];
    }
}
__global__ __launch_bounds__(TPB) void k_fillP(const int* Pr, const int* Pc, const float* Pv,
                                               const float* dPv, int* curP,
                                               int2* pP, float* dvalP) {
    long k = (long)blockIdx.x * TPB + threadIdx.x;
    if (k < NNZ_P) {
        int pos = atomicAdd(&curP[Pr[k]], 1);
        pP[pos] = make_int2(Pc[k], __float_as_int(Pv[k]));
        dvalP[pos] = dPv[k];
    }
}

// ---------------- generic CSR gather SpMV (setup) ----------------
__global__ __launch_bounds__(TPB) void k_csr(const int* rptr, const int2* pair,
                                             const double* vin, double* vout,
                                             double sgn, int accum, int nrows) {
    int i = blockIdx.x * TPB + threadIdx.x;
    if (i >= nrows) return;
    double s = row_dot(pair, rptr[i], rptr[i + 1], vin) * sgn;
    vout[i] = accum ? (vout[i] + s) : s;
}

__global__ __launch_bounds__(TPB) void k_csr_d(const int* rptr, const int2* pair,
                                               const float* dval, const double* vin,
                                               double* vout, double sgn, int accum, int nrows) {
    int i = blockIdx.x * TPB + threadIdx.x;
    if (i >= nrows) return;
    double s = row_dot_d(pair, dval, rptr[i], rptr[i + 1], vin) * sgn;
    vout[i] = accum ? (vout[i] + s) : s;
}

// ---------------- dots & small elementwise (unchanged math) ----------------
__global__ __launch_bounds__(TPB) void k_dot_fd(const float* a, const double* b, long len, double* dst) {
    long i = (long)blockIdx.x * TPB + threadIdx.x;
    double loc = 0.0;
    if (i < len) loc = (double)a[i] * b[i];
    blk_red_add(loc, dst);
}
__global__ __launch_bounds__(TPB) void k_dot_ff(const float* a, const float* b, long len, double* dst) {
    long i = (long)blockIdx.x * TPB + threadIdx.x;
    double loc = 0.0;
    if (i < len) loc = (double)a[i] * (double)b[i];
    blk_red_add(loc, dst);
}
__global__ __launch_bounds__(TPB) void k_c3e(const float* q, const double* Px, double* c3) {
    int i = blockIdx.x * TPB + threadIdx.x;
    if (i < N_DIM) c3[i] = (double)q[i] + 2.0 * Px[i];
}
__global__ __launch_bounds__(TPB) void k_dd_n(const double* dpx, const float* dq, double* dd) {
    int i = blockIdx.x * TPB + threadIdx.x;
    if (i < N_DIM) dd[i] = dpx[i] + (double)dq[i];
}
__global__ __launch_bounds__(TPB) void k_dd_m(const float* db, double* dd) {
    int j = blockIdx.x * TPB + threadIdx.x;
    if (j < M_DIM) dd[N_DIM + j] += (double)db[j];
}
__global__ __launch_bounds__(64) void k_dd_t(double* sc, double* dd) {
    if (threadIdx.x == 0) dd[NMSUM] = -sc[1] - sc[2] - sc[3];
}
__global__ __launch_bounds__(TPB) void k_neg(double* dd) {
    int i = blockIdx.x * TPB + threadIdx.x;
    if (i < NM1) dd[i] = -dd[i];
}
__global__ __launch_bounds__(TPB) void k_ft_n(const double* c3, const double* W, double* U) {
    int i = blockIdx.x * TPB + threadIdx.x;
    if (i < N_DIM) U[i] = U[i] - c3[i] * W[NMSUM];
}
__global__ __launch_bounds__(TPB) void k_ft_m(const double* mask_d, const float* b,
                                              const double* tm, const double* W, double* U) {
    int j = blockIdx.x * TPB + threadIdx.x;
    if (j < M_DIM) {
        double wt = W[NMSUM];
        double tmv = tm[j] - (double)b[j] * wt;
        double wm = W[N_DIM + j];
        U[N_DIM + j] = mask_d[j] * (tmv - wm) + wm;
    }
}
__global__ __launch_bounds__(64) void k_ft_t(const double* e1, const double* e2, const double* xtpx,
                                             const double* W, double* U) {
    if (threadIdx.x == 0) U[NMSUM] = (*e1) + (*e2) + (*xtpx) * W[NMSUM];
}
__global__ __launch_bounds__(TPB) void k_cginit(const double* r, double* p, double* gam0) {
    int i = blockIdx.x * TPB + threadIdx.x;
    double loc = 0.0;
    if (i < NM1) { double v = r[i]; p[i] = v; loc = v * v; }
    blk_red_add(loc, gam0);
}

// ---------------- fused per-iteration kernels (4 launches/iter) ----------------
// K1: p-update + um + d1 = c3.p_n, d2 = b.um
__global__ __launch_bounds__(TPB) void k_iterA(const double* r, double* p,
                                               const double* mask_d, const double* c3,
                                               const float* b, double* um,
                                               double* sc, int it) {
    long i = (long)blockIdx.x * TPB + threadIdx.x;
    double* gam = sc + 432;
    double* base = sc + 16 + 8 * it;
    double l1 = 0.0, l2 = 0.0;
    if (i < NM1) {
        double pn;
        if (it > 0) {
            double beta = gam[it] / gam[it - 1];
            pn = r[i] + beta * p[i];
            p[i] = pn;
        } else {
            pn = p[i];
        }
        if (i < N_DIM) {
            l1 = c3[i] * pn;
        } else if (i < NMSUM) {
            int j = (int)(i - N_DIM);
            double u = mask_d[j] * pn;
            um[j] = u;
            l2 = (double)b[j] * u;
        }
    }
    blk_red_add(l1, base);       // d1
    blk_red_add(l2, base + 1);   // d2
}

// K2: Fmv — CSR gathers (unrolled) + elementwise finish + e1,e2 dots
__global__ __launch_bounds__(TPB) void k_fmv(const int* __restrict__ rptrP, const int2* __restrict__ pP,
                                             const int* __restrict__ rptrAc, const int2* __restrict__ pAc,
                                             const int* __restrict__ rptrAr, const int2* __restrict__ pAr,
                                             const float* __restrict__ q, const float* __restrict__ b,
                                             const double* __restrict__ p, const double* __restrict__ um,
                                             double* __restrict__ Fp, double* sc, int it) {
    long i = (long)blockIdx.x * TPB + threadIdx.x;
    double* base = sc + 16 + 8 * it;
    double ut = p[NMSUM];
    double l1 = 0.0, l2 = 0.0;
    if (i < N_DIM) {
        double s = row_dot(pP, rptrP[i], rptrP[i + 1], p)
                 + row_dot(pAc, rptrAc[i], rptrAc[i + 1], um);
        double r1 = s + (double)q[i] * ut;
        double v = (r1 - p[i]) + p[i];
        Fp[i] = v;
        l1 = (double)q[i] * v;
    } else if (i < NMSUM) {
        int j = (int)(i - N_DIM);
        double s = row_dot(pAr, rptrAr[j], rptrAr[j + 1], p);
        double r2 = -s + (double)b[j] * ut;
        double v = (r2 - um[j]) + p[i];
        Fp[i] = v;
        l2 = (double)b[j] * v;
    } else if (i == NMSUM) {
        double r3 = -base[0] - base[1] + sc[0] * ut;
        Fp[NMSUM] = (r3 - ut) + ut;
    }
    blk_red_add(l1, base + 2);   // e1
    blk_red_add(l2, base + 3);   // e2
}

// K3: FTmv — CSR gathers (unrolled) + elementwise finish + pq dot
__global__ __launch_bounds__(TPB) void k_ftmv(const int* __restrict__ rptrP, const int2* __restrict__ pP,
                                              const int* __restrict__ rptrAc, const int2* __restrict__ pAc,
                                              const int* __restrict__ rptrAr, const int2* __restrict__ pAr,
                                              const float* __restrict__ b, const double* __restrict__ mask_d,
                                              const double* __restrict__ c3,
                                              const double* __restrict__ Fp, const double* __restrict__ p,
                                              double* __restrict__ Ap, double* sc, int it) {
    long i = (long)blockIdx.x * TPB + threadIdx.x;
    double* base = sc + 16 + 8 * it;
    double wt = Fp[NMSUM];
    double l = 0.0;
    if (i < N_DIM) {
        double s = row_dot(pP, rptrP[i], rptrP[i + 1], Fp)
                 - row_dot(pAc, rptrAc[i], rptrAc[i + 1], Fp + N_DIM);
        double v = s - c3[i] * wt;
        Ap[i] = v;
        l = p[i] * v;
    } else if (i < NMSUM) {
        int j = (int)(i - N_DIM);
        double s = row_dot(pAr, rptrAr[j], rptrAr[j + 1], Fp);
        double tmv = s - (double)b[j] * wt;
        double wm = Fp[i];
        double v = mask_d[j] * (tmv - wm) + wm;
        Ap[i] = v;
        l = p[i] * v;
    } else if (i == NMSUM) {
        double tt = base[2] + base[3] + sc[0] * wt;
        Ap[i] = tt;
        l = p[i] * tt;
    }
    blk_red_add(l, base + 4);   // pq
}

// K4: x,r update + gam[it+1]
__global__ __launch_bounds__(TPB) void k_upd(const double* p, const double* Ap,
                                             double* xcg, double* r, double* sc, int it) {
    long i = (long)blockIdx.x * TPB + threadIdx.x;
    double* gam = sc + 432;
    double* base = sc + 16 + 8 * it;
    double alpha = gam[it] / base[4];
    double l = 0.0;
    if (i < NM1) {
        xcg[i] += alpha * p[i];
        double rn = r[i] - alpha * Ap[i];
        r[i] = rn;
        l = rn * rn;
    }
    blk_red_add(l, &gam[it + 1]);
}

__global__ __launch_bounds__(TPB) void k_final(const double* xcg, const double* mask_d,
                                               const float* x, const float* y, const float* s,
                                               float* out) {
    int i = blockIdx.x * TPB + threadIdx.x;
    double dzt = xcg[NMSUM];
    if (i < N_DIM) {
        out[i] = (float)(xcg[i] - (double)x[i] * dzt);
    } else if (i < NMSUM) {
        int j = i - N_DIM;
        double dzm = xcg[N_DIM + j];
        double t = mask_d[j] * dzm;
        out[N_DIM + j] = (float)(t - (double)y[j] * dzt);
        out[N_DIM + M_DIM + j] = (float)(t - dzm - (double)s[j] * dzt);
    }
}

extern "C" void kernel_launch(void* const* d_in, const int* in_sizes, int n_in,
                              void* d_out, int out_size, void* d_ws, size_t ws_size,
                              hipStream_t stream) {
    const int*   Pr  = (const int*)d_in[0];
    const int*   Pc  = (const int*)d_in[1];
    const float* Pv  = (const float*)d_in[2];
    const int*   Ar  = (const int*)d_in[3];
    const int*   Ac  = (const int*)d_in[4];
    const float* Av  = (const float*)d_in[5];
    const float* q   = (const float*)d_in[6];
    const float* b   = (const float*)d_in[7];
    const float* x   = (const float*)d_in[8];
    const float* yv  = (const float*)d_in[9];
    const float* sv  = (const float*)d_in[10];
    const float* dPv = (const float*)d_in[11];
    const float* dAv = (const float*)d_in[12];
    const float* dq  = (const float*)d_in[13];
    const float* db  = (const float*)d_in[14];
    float* out = (float*)d_out;

    char* wp = (char*)d_ws;
    auto alloc = [&](size_t bytes) { char* r0 = wp; wp += (bytes + 255) & ~255ull; return r0; };

    double* sc     = (double*)alloc(NSLOT * 8);
    double* mask_d = (double*)alloc((size_t)M_DIM * 8);
    double* pim_d  = (double*)alloc((size_t)M_DIM * 8);
    double* xd     = (double*)alloc((size_t)N_DIM * 8);
    double* Px     = (double*)alloc((size_t)N_DIM * 8);
    double* dpx    = (double*)alloc((size_t)N_DIM * 8);
    double* c3     = (double*)alloc((size_t)N_DIM * 8);
    double* um     = (double*)alloc((size_t)M_DIM * 8);
    double* tm     = (double*)alloc((size_t)M_DIM * 8);
    double* dd     = (double*)alloc((size_t)NM1 * 8);
    double* r      = (double*)alloc((size_t)NM1 * 8);
    double* p      = (double*)alloc((size_t)NM1 * 8);
    double* xcg    = (double*)alloc((size_t)NM1 * 8);
    double* Fp     = (double*)alloc((size_t)NM1 * 8);
    double* Ap     = (double*)alloc((size_t)NM1 * 8);
    int2*  pAr    = (int2*)alloc((size_t)NNZ_A * 8);
    int2*  pAc    = (int2*)alloc((size_t)NNZ_A * 8);
    int2*  pP     = (int2*)alloc((size_t)NNZ_P * 8);
    float* dvalAr = (float*)alloc((size_t)NNZ_A * 4);
    float* dvalAc = (float*)alloc((size_t)NNZ_A * 4);
    float* dvalP  = (float*)alloc((size_t)NNZ_P * 4);
    int*   rptrAr = (int*)alloc((size_t)(M_DIM + 1) * 4);
    int*   rptrAc = (int*)alloc((size_t)(N_DIM + 1) * 4);
    int*   rptrP  = (int*)alloc((size_t)(N_DIM + 1) * 4);
    int*   cntR   = (int*)alloc((size_t)M_DIM * 4);   // reused as cursor
    int*   cntC   = (int*)alloc((size_t)N_DIM * 4);
    int*   cntP   = (int*)alloc((size_t)N_DIM * 4);
    int*   blks   = (int*)alloc(1024 * 4);

    double* xtpx = sc + 0;
    double* gam  = sc + 432;

    auto g = [](long n) { return dim3((unsigned)((n + TPB - 1) / TPB)); };

    // ---- CSR build ----
    hipLaunchKernelGGL(k_init, g(NM1), dim3(TPB), 0, stream, sc, yv, sv, x, mask_d, pim_d, xd, xcg, cntR, cntC, cntP);
    hipLaunchKernelGGL(k_hist, g(NNZ_A), dim3(TPB), 0, stream, Ar, Ac, Pr, cntR, cntC, cntP);

    auto scan = [&](int* cnt, int len, int* rptr) {
        int nb = (len + TPB - 1) / TPB;
        hipLaunchKernelGGL(k_scan1, dim3((unsigned)nb), dim3(TPB), 0, stream, cnt, len, rptr, blks);
        hipLaunchKernelGGL(k_scan2, dim3(1), dim3(1024), 0, stream, blks, nb, rptr + len);
        hipLaunchKernelGGL(k_scan3, dim3((unsigned)nb), dim3(TPB), 0, stream, rptr, blks, len, cnt);
    };
    scan(cntR, M_DIM, rptrAr);   // cntR becomes cursor
    scan(cntC, N_DIM, rptrAc);
    scan(cntP, N_DIM, rptrP);

    hipLaunchKernelGGL(k_fillAr, g(NNZ_A), dim3(TPB), 0, stream, Ar, Ac, Av, dAv, cntR, pAr, dvalAr);
    hipLaunchKernelGGL(k_fillAc, g(NNZ_A), dim3(TPB), 0, stream, Ar, Ac, Av, dAv, cntC, pAc, dvalAc);
    hipLaunchKernelGGL(k_fillP,  g(NNZ_P), dim3(TPB), 0, stream, Pr, Pc, Pv, dPv, cntP, pP, dvalP);

    // ---- setup math ----
    hipLaunchKernelGGL(k_csr, g(N_DIM), dim3(TPB), 0, stream, rptrP, pP, xd, Px, 1.0, 0, N_DIM);          // Px = P x
    hipLaunchKernelGGL(k_dot_fd, g(N_DIM), dim3(TPB), 0, stream, x, Px, (long)N_DIM, xtpx);
    hipLaunchKernelGGL(k_c3e, g(N_DIM), dim3(TPB), 0, stream, q, Px, c3);
    hipLaunchKernelGGL(k_csr_d, g(N_DIM), dim3(TPB), 0, stream, rptrP, pP, dvalP, xd, dpx, 1.0, 0, N_DIM); // dpx = dP x
    hipLaunchKernelGGL(k_dd_n, g(N_DIM), dim3(TPB), 0, stream, dpx, dq, dd);
    hipLaunchKernelGGL(k_csr_d, g(N_DIM), dim3(TPB), 0, stream, rptrAc, pAc, dvalAc, pim_d, dd, 1.0, 1, N_DIM);   // += dA^T pim
    hipLaunchKernelGGL(k_csr_d, g(M_DIM), dim3(TPB), 0, stream, rptrAr, pAr, dvalAr, xd, dd + N_DIM, -1.0, 0, M_DIM); // -dA x
    hipLaunchKernelGGL(k_dd_m, g(M_DIM), dim3(TPB), 0, stream, db, dd);
    hipLaunchKernelGGL(k_dot_ff, g(N_DIM), dim3(TPB), 0, stream, dq, x, (long)N_DIM, sc + 1);
    hipLaunchKernelGGL(k_dot_fd, g(M_DIM), dim3(TPB), 0, stream, db, pim_d, (long)M_DIM, sc + 2);
    hipLaunchKernelGGL(k_dot_fd, g(N_DIM), dim3(TPB), 0, stream, x, dpx, (long)N_DIM, sc + 3);
    hipLaunchKernelGGL(k_dd_t, dim3(1), dim3(64), 0, stream, sc, dd);
    hipLaunchKernelGGL(k_neg, g(NM1), dim3(TPB), 0, stream, dd);
    hipLaunchKernelGGL(k_csr, g(N_DIM), dim3(TPB), 0, stream, rptrP, pP, dd, r, 1.0, 0, N_DIM);            // r_n = P wn
    hipLaunchKernelGGL(k_csr, g(N_DIM), dim3(TPB), 0, stream, rptrAc, pAc, dd + N_DIM, r, -1.0, 1, N_DIM); // -= A^T wm
    hipLaunchKernelGGL(k_ft_n, g(N_DIM), dim3(TPB), 0, stream, c3, dd, r);
    hipLaunchKernelGGL(k_csr, g(M_DIM), dim3(TPB), 0, stream, rptrAr, pAr, dd, tm, 1.0, 0, M_DIM);         // tm = A wn
    hipLaunchKernelGGL(k_ft_m, g(M_DIM), dim3(TPB), 0, stream, mask_d, b, tm, dd, r);
    hipLaunchKernelGGL(k_dot_fd, g(N_DIM), dim3(TPB), 0, stream, q, dd, (long)N_DIM, sc + 8);
    hipLaunchKernelGGL(k_dot_fd, g(M_DIM), dim3(TPB), 0, stream, b, dd + N_DIM, (long)M_DIM, sc + 9);
    hipLaunchKernelGGL(k_ft_t, dim3(1), dim3(64), 0, stream, sc + 8, sc + 9, xtpx, dd, r);
    hipLaunchKernelGGL(k_cginit, g(NM1), dim3(TPB), 0, stream, r, p, gam);

    // ---- 20 CG iterations, 4 fused launches each ----
    for (int it = 0; it < CG_ITERS; ++it) {
        hipLaunchKernelGGL(k_iterA, g(NM1), dim3(TPB), 0, stream, r, p, mask_d, c3, b, um, sc, it);
        hipLaunchKernelGGL(k_fmv,   g(NM1), dim3(TPB), 0, stream, rptrP, pP, rptrAc, pAc, rptrAr, pAr,
                           q, b, p, um, Fp, sc, it);
        hipLaunchKernelGGL(k_ftmv,  g(NM1), dim3(TPB), 0, stream, rptrP, pP, rptrAc, pAc, rptrAr, pAr,
                           b, mask_d, c3, Fp, p, Ap, sc, it);
        hipLaunchKernelGGL(k_upd,   g(NM1), dim3(TPB), 0, stream, p, Ap, xcg, r, sc, it);
    }

    hipLaunchKernelGGL(k_final, g(NMSUM), dim3(TPB), 0, stream, xcg, mask_d, x, yv, sv, out);
}